// Round 1
// baseline (205.149 us; speedup 1.0000x reference)
//
#include <hip/hip_runtime.h>
#include <hip/hip_bf16.h>

// Tokenizer: masked row compaction.
//   inputs:  hidden_states (B,L,D) fp32, token_mask (B,L) int (0/1)
//   outputs: chunked (B,M,D) fp32 left-packed zero-padded, counts (B,) as floats
// d_out layout (flat fp32): [B*M*D chunked][B counts]
// Workspace layout: [64 ints counts (padded)][B*M ints src_idx]

// Kernel 1: per-row block scan of the mask -> inverse index map + counts.
// One block of 256 threads per batch row; each thread owns a contiguous
// L/256-element segment of the mask (sequential per-thread scan + block scan).
__global__ void scan_kernel(const int* __restrict__ mask,
                            int* __restrict__ src_idx,
                            int* __restrict__ counts_ws,
                            float* __restrict__ counts_out,
                            int L, int M) {
    const int b = blockIdx.x;
    const int t = threadIdx.x;            // 0..255
    const int nthreads = blockDim.x;      // 256
    const int per = L / nthreads;         // 16 for L=4096
    const int* row = mask + (size_t)b * L;
    const int base = t * per;

    // pass 1: local sum
    int s = 0;
    for (int i = 0; i < per; ++i) s += (row[base + i] != 0);

    __shared__ int sums[256];
    sums[t] = s;
    __syncthreads();

    // Hillis-Steele inclusive scan over 256 thread sums
    for (int off = 1; off < nthreads; off <<= 1) {
        int v = (t >= off) ? sums[t - off] : 0;
        __syncthreads();
        sums[t] += v;
        __syncthreads();
    }

    const int total = sums[nthreads - 1];
    int prefix = (t == 0) ? 0 : sums[t - 1];  // exclusive prefix for this segment

    // pass 2: scatter source indices into the inverse map
    int* srow = src_idx + (size_t)b * M;
    for (int i = 0; i < per; ++i) {
        if (row[base + i] != 0) {
            srow[prefix] = base + i;
            ++prefix;
        }
    }

    if (t == 0) {
        counts_ws[b] = total;
        counts_out[b] = (float)total;   // harness reads output flat as fp32
    }
}

// Kernel 2: one block per output row (b, m). Copy the selected source row
// (4 KiB, float4-vectorized, coalesced) or write zeros for padding slots.
__global__ void pack_kernel(const float4* __restrict__ hidden,
                            const int* __restrict__ src_idx,
                            const int* __restrict__ counts,
                            float4* __restrict__ out,
                            int L, int M, int D4) {
    const int m = blockIdx.x;
    const int b = blockIdx.y;
    const size_t orow = ((size_t)b * M + m) * D4;

    if (m < counts[b]) {
        const int l = src_idx[(size_t)b * M + m];
        const size_t irow = ((size_t)b * L + l) * D4;
        for (int t = threadIdx.x; t < D4; t += blockDim.x)
            out[orow + t] = hidden[irow + t];
    } else {
        const float4 z = make_float4(0.f, 0.f, 0.f, 0.f);
        for (int t = threadIdx.x; t < D4; t += blockDim.x)
            out[orow + t] = z;
    }
}

extern "C" void kernel_launch(void* const* d_in, const int* in_sizes, int n_in,
                              void* d_out, int out_size, void* d_ws, size_t ws_size,
                              hipStream_t stream) {
    const int B = 8;                       // per setup_inputs()
    const int BL = in_sizes[1];            // B*L = 32768
    const int D  = in_sizes[0] / BL;       // 1024
    const int L  = BL / B;                 // 4096
    const int M  = (out_size - B) / (B * D);

    const float* hidden = (const float*)d_in[0];
    const int*   mask   = (const int*)d_in[1];
    float*       out    = (float*)d_out;

    int* counts_ws = (int*)d_ws;           // 8 ints, padded to 64
    int* src_idx   = (int*)d_ws + 64;      // B*M ints

    float* counts_out = out + (size_t)B * M * D;

    scan_kernel<<<B, 256, 0, stream>>>(mask, src_idx, counts_ws, counts_out, L, M);

    if (M > 0) {
        dim3 grid(M, B);
        pack_kernel<<<grid, 256, 0, stream>>>((const float4*)hidden, src_idx,
                                              counts_ws, (float4*)out, L, M, D / 4);
    }
}

// Round 2
// 203.740 us; speedup vs baseline: 1.0069x; 1.0069x over previous
//
#include <hip/hip_runtime.h>
#include <hip/hip_bf16.h>

// Tokenizer: masked row compaction.
//   inputs:  hidden_states (B,L,D) fp32, token_mask (B,L) int32 (0/1)
//   outputs: chunked (B,M,D) fp32 left-packed zero-padded, counts (B,) as floats
// d_out layout (flat fp32): [B*M*D chunked][B counts]
// Workspace layout: [64 ints counts (padded)][B*M ints src_idx]

// Kernel 1: per-row scan of the mask -> inverse index map + counts.
// One block of 1024 threads per batch row; each thread owns 4 contiguous
// mask elements (int4 load). Wave-shuffle inclusive scan + 16-wave LDS scan.
__global__ __launch_bounds__(1024) void scan_kernel(
        const int* __restrict__ mask,
        int* __restrict__ src_idx,
        int* __restrict__ counts_ws,
        float* __restrict__ counts_out,
        int L, int M) {
    const int b = blockIdx.x;
    const int t = threadIdx.x;            // 0..1023
    const int lane = t & 63;
    const int wid  = t >> 6;              // 0..15
    const int base = t * 4;               // 4 elems/thread, L = 4096

    const int4 v = *(const int4*)(mask + (size_t)b * L + base);
    const int m0 = (v.x != 0), m1 = (v.y != 0), m2 = (v.z != 0), m3 = (v.w != 0);
    const int s = m0 + m1 + m2 + m3;

    // inclusive scan of s within the 64-lane wave
    int incl = s;
    #pragma unroll
    for (int off = 1; off < 64; off <<= 1) {
        int up = __shfl_up(incl, off, 64);
        if (lane >= off) incl += up;
    }

    __shared__ int wsum[16];    // per-wave totals
    __shared__ int wexc[17];    // exclusive offsets per wave + grand total
    if (lane == 63) wsum[wid] = incl;
    __syncthreads();
    if (t == 0) {
        int acc = 0;
        #pragma unroll
        for (int w = 0; w < 16; ++w) { wexc[w] = acc; acc += wsum[w]; }
        wexc[16] = acc;
        counts_ws[b] = acc;
        counts_out[b] = (float)acc;   // harness reads output flat as fp32
    }
    __syncthreads();

    // exclusive prefix for this thread's 4-element segment
    int prefix = wexc[wid] + (incl - s);

    int* srow = src_idx + (size_t)b * M;
    if (m0) srow[prefix++] = base + 0;
    if (m1) srow[prefix++] = base + 1;
    if (m2) srow[prefix++] = base + 2;
    if (m3) srow[prefix]   = base + 3;
}

// Kernel 2: grid-stride over output rows; 2048 fat blocks keep ~8 rows in
// flight per block. Each row is 256 float4 = exactly one float4 per thread.
__global__ __launch_bounds__(256) void pack_kernel(
        const float4* __restrict__ hidden,
        const int* __restrict__ src_idx,
        const int* __restrict__ counts,
        float4* __restrict__ out,
        int L, int M, int D4, int nrows) {
    const int t = threadIdx.x;
    for (int r = blockIdx.x; r < nrows; r += gridDim.x) {
        const int b = r / M;
        const int m = r - b * M;
        const size_t orow = (size_t)r * D4;
        if (m < counts[b]) {
            const int l = src_idx[r];
            const size_t irow = ((size_t)b * L + l) * D4;
            for (int i = t; i < D4; i += blockDim.x)
                out[orow + i] = hidden[irow + i];
        } else {
            const float4 z = make_float4(0.f, 0.f, 0.f, 0.f);
            for (int i = t; i < D4; i += blockDim.x)
                out[orow + i] = z;
        }
    }
}

extern "C" void kernel_launch(void* const* d_in, const int* in_sizes, int n_in,
                              void* d_out, int out_size, void* d_ws, size_t ws_size,
                              hipStream_t stream) {
    const int B = 8;                       // per setup_inputs()
    const int BL = in_sizes[1];            // B*L = 32768
    const int D  = in_sizes[0] / BL;       // 1024
    const int L  = BL / B;                 // 4096
    const int M  = (out_size - B) / (B * D);

    const float* hidden = (const float*)d_in[0];
    const int*   mask   = (const int*)d_in[1];
    float*       out    = (float*)d_out;

    int* counts_ws = (int*)d_ws;           // 8 ints, padded to 64
    int* src_idx   = (int*)d_ws + 64;      // B*M ints

    float* counts_out = out + (size_t)B * M * D;

    scan_kernel<<<B, 1024, 0, stream>>>(mask, src_idx, counts_ws, counts_out, L, M);

    if (M > 0) {
        const int nrows = B * M;
        int grid = nrows < 2048 ? nrows : 2048;
        pack_kernel<<<grid, 256, 0, stream>>>((const float4*)hidden, src_idx,
                                              counts_ws, (float4*)out, L, M,
                                              D / 4, nrows);
    }
}